// Round 11
// baseline (506.116 us; speedup 1.0000x reference)
//
#include <hip/hip_runtime.h>

#define NB 1024
#define NT 256
#define IND 10
#define HID 64

// Packed weight array Wp (float offsets), all [k][64j] lane-coalesced:
//   OFF_WA [120][64]: W1[11+q]+W1[132+q]   (q = qmap(k))
//   OFF_WB [120][64]: W1[253+q]            (gated by rel0)
//   OFF_WC [120][64]: W1[374+q]            (gated by rel1)
//   OFF_WD [16][64] : rel2-gated 17-term weights (sig2f[1..16] part)
//   OFF_WX [28][64] : 0-9 wrel, 10-19 wf, 20-23 tt coefs (ws,wb,wc,wd),
//                     24 w_one, 25 b1, 26-27 pad
#define OFF_WA 0
#define OFF_WB 7680
#define OFF_WC 15360
#define OFF_WD 23040
#define OFF_WX 24064
#define WP_FLOATS 25856

__device__ __forceinline__ int qmap(int kk) {
    if (kk < 10) return 1 + kk;
    if (kk < 20) return 11 * (kk - 10 + 1);
    int i = (kk - 20) / 10, c = (kk - 20) % 10;
    return 11 * (i + 1) + 1 + c;
}

__global__ void pack_kernel(const float* __restrict__ W1, const float* __restrict__ b1,
                            float* __restrict__ Wp) {
    int idx = blockIdx.x * 256 + threadIdx.x;
    if (idx >= WP_FLOATS) return;
    float v = 0.f;
    if (idx < OFF_WB) {
        int k = idx >> 6, j = idx & 63; int q = qmap(k);
        v = W1[(11 + q) * 64 + j] + W1[(132 + q) * 64 + j];
    } else if (idx < OFF_WC) {
        int e = idx - OFF_WB; int k = e >> 6, j = e & 63;
        v = W1[(253 + qmap(k)) * 64 + j];
    } else if (idx < OFF_WD) {
        int e = idx - OFF_WC; int k = e >> 6, j = e & 63;
        v = W1[(374 + qmap(k)) * 64 + j];
    } else if (idx < OFF_WX) {
        int e = idx - OFF_WD; int i = e >> 6, j = e & 63;
        if (i < 10)       v = W1[(496 + i) * 64 + j];
        else if (i == 10) v = W1[506 * 64 + j];
        else if (i < 16)  v = W1[(507 + (i - 11)) * 64 + j];
    } else {
        int e = idx - OFF_WX; int o = e >> 6, j = e & 63;
        if (o < 10)       v = W1[(1 + o) * 64 + j];
        else if (o < 20)  v = W1[(512 + o - 10) * 64 + j];
        else if (o == 20) v = W1[11 * 64 + j] + W1[132 * 64 + j];
        else if (o == 21) v = W1[253 * 64 + j];
        else if (o == 22) v = W1[374 * 64 + j];
        else if (o == 23) v = W1[495 * 64 + j];
        else if (o == 24) v = W1[0 * 64 + j];
        else if (o == 25) v = b1[j];
    }
    Wp[idx] = v;
}

// ---------------------------------------------------------------------------
// presig v6 (unchanged from r10: 298 us, spill-free, VALUBusy 65%).
// ---------------------------------------------------------------------------
__global__ __launch_bounds__(256, 1) void presig6_kernel(
    const float* __restrict__ features, const float* __restrict__ Wp,
    float* __restrict__ pre1) {
    const int b = blockIdx.x;
    const int tid = threadIdx.x;
    const int l = tid & 63;
    const int wu = tid >> 6;

    __shared__ __align__(16) float sF[NT * IND];
    __shared__ __align__(16) float sP[64 * 132];
    __shared__ __align__(16) float sAcc[2][16 * 4 * 64];
    __shared__ float sBase[128];

    {
        const float4* src = (const float4*)(features + b * (NT * IND));
        float4* dst = (float4*)sF;
        for (int e = tid; e < NT * IND / 4; e += 256) dst[e] = src[e];
    }
    float f0[IND];
#pragma unroll
    for (int c = 0; c < IND; ++c) f0[c] = features[b * (NT * IND) + c];

    float wxv[26];
#pragma unroll
    for (int o = 0; o < 26; ++o) wxv[o] = Wp[OFF_WX + o * 64 + l];

    if (tid < 128) sBase[tid] = 0.f;
    __syncthreads();   // B0

    for (int tile = 0; tile < 4; ++tile) {
        const int t0 = tile * 64;

        const int r = t0 + l;
        float rf = (float)r;
        float fr[IND], rel[IND], inc[IND];
#pragma unroll
        for (int c = 0; c < IND; ++c) fr[c] = sF[r * IND + c];
#pragma unroll
        for (int c = 0; c < IND; ++c) rel[c] = fr[c] - f0[c];
        {
            bool last = (r >= NT - 1);
#pragma unroll
            for (int c = 0; c < IND; ++c)
                inc[c] = last ? 0.f : (sF[(r + 1) * IND + c] - fr[c]);
        }
        float p[30], own[30];
        if (wu == 0) {
#pragma unroll
            for (int c = 0; c < 10; ++c) p[c] = rf * inc[c];
#pragma unroll
            for (int i = 0; i < 10; ++i) p[10 + i] = rel[i];
#pragma unroll
            for (int c = 0; c < 10; ++c) p[20 + c] = rel[0] * inc[c];
        } else {
            const int i0 = 3 * wu - 2;
#pragma unroll
            for (int q = 0; q < 30; ++q) {
                int i = i0 + q / 10, c = q % 10;
                p[q] = rel[i] * inc[c];
            }
        }
#pragma unroll
        for (int i = 0; i < 30; ++i) own[i] = p[i];
#pragma unroll
        for (int dsh = 0; dsh < 6; ++dsh) {
            const int d = 1 << dsh;
            bool ok = (l >= d);
#pragma unroll
            for (int i = 0; i < 30; ++i) {
                float v = __shfl_up(p[i], d, 64);
                if (ok) p[i] += v;
            }
        }
        float inv_r = (r > 0) ? 1.f / rf : 0.f;
#pragma unroll
        for (int i = 0; i < 30; ++i) {
            float v = sBase[wu * 32 + i] + p[i] - own[i];
            if (wu == 0 && i < 20) v *= inv_r;
            sP[l * 132 + 32 * wu + i] = v;
        }
        if (l == 63) {
#pragma unroll
            for (int i = 0; i < 30; ++i) sBase[wu * 32 + i] += p[i];
        }
        __syncthreads();   // Bb

        int kbase = 30 * wu;
        asm volatile("" : "+v"(kbase));
        float wav[30], wbv[30], wcv[30];
#pragma unroll
        for (int i = 0; i < 30; ++i) {
            int k = kbase + i;
            wav[i] = Wp[OFF_WA + (k << 6) + l];
            wbv[i] = Wp[OFF_WB + (k << 6) + l];
            wcv[i] = Wp[OFF_WC + (k << 6) + l];
        }
        float wdv[16];
#pragma unroll
        for (int i = 0; i < 16; ++i) wdv[i] = Wp[OFF_WD + (i << 6) + l];

#pragma unroll 1
        for (int tq = 0; tq < 4; ++tq) {
            float* buf = sAcc[tq & 1];
#pragma unroll 1
            for (int u = 0; u < 16; ++u) {
                int t = tq * 16 + u;
                const float4* Pp = (const float4*)&sP[t * 132 + 32 * wu];
                float4 q0 = Pp[0], q1 = Pp[1], q2 = Pp[2], q3 = Pp[3];
                float4 q4 = Pp[4], q5 = Pp[5], q6 = Pp[6], q7 = Pp[7];
                float rr0 = sF[(t0 + t) * IND + 0] - f0[0];
                float rr1 = sF[(t0 + t) * IND + 1] - f0[1];
                float rr2 = sF[(t0 + t) * IND + 2] - f0[2];
                float a = 0.f, bb = 0.f, cv = 0.f;
#define FMA4(QQ, BASE) \
                a  = fmaf(QQ.x, wav[BASE+0], a);  a  = fmaf(QQ.y, wav[BASE+1], a); \
                a  = fmaf(QQ.z, wav[BASE+2], a);  a  = fmaf(QQ.w, wav[BASE+3], a); \
                bb = fmaf(QQ.x, wbv[BASE+0], bb); bb = fmaf(QQ.y, wbv[BASE+1], bb); \
                bb = fmaf(QQ.z, wbv[BASE+2], bb); bb = fmaf(QQ.w, wbv[BASE+3], bb); \
                cv = fmaf(QQ.x, wcv[BASE+0], cv); cv = fmaf(QQ.y, wcv[BASE+1], cv); \
                cv = fmaf(QQ.z, wcv[BASE+2], cv); cv = fmaf(QQ.w, wcv[BASE+3], cv);
                FMA4(q0, 0) FMA4(q1, 4) FMA4(q2, 8) FMA4(q3, 12)
                FMA4(q4, 16) FMA4(q5, 20) FMA4(q6, 24)
#undef FMA4
                a  = fmaf(q7.x, wav[28], a);  a  = fmaf(q7.y, wav[29], a);
                bb = fmaf(q7.x, wbv[28], bb); bb = fmaf(q7.y, wbv[29], bb);
                cv = fmaf(q7.x, wcv[28], cv); cv = fmaf(q7.y, wcv[29], cv);
                float val = a + rr0 * bb + rr1 * cv;
                if (wu == 0) {
                    float dd = 0.f;
                    dd = fmaf(q0.x, wdv[0], dd); dd = fmaf(q0.y, wdv[1], dd);
                    dd = fmaf(q0.z, wdv[2], dd); dd = fmaf(q0.w, wdv[3], dd);
                    dd = fmaf(q1.x, wdv[4], dd); dd = fmaf(q1.y, wdv[5], dd);
                    dd = fmaf(q1.z, wdv[6], dd); dd = fmaf(q1.w, wdv[7], dd);
                    dd = fmaf(q2.x, wdv[8], dd); dd = fmaf(q2.y, wdv[9], dd);
                    dd = fmaf(q2.z, wdv[10], dd);
                    dd = fmaf(q5.x, wdv[11], dd); dd = fmaf(q5.y, wdv[12], dd);
                    dd = fmaf(q5.z, wdv[13], dd); dd = fmaf(q5.w, wdv[14], dd);
                    dd = fmaf(q6.x, wdv[15], dd);
                    val = fmaf(rr2, dd, val);
                }
                buf[(u * 4 + wu) * 64 + l] = val;
            }
            __syncthreads();   // Bq1
#pragma unroll 1
            for (int u = 0; u < 4; ++u) {
                int uu = wu * 4 + u;
                int t = tq * 16 + uu;
                int rr = t0 + t;
                float rf2 = (float)rr;
                float inv2 = (rr > 0) ? 1.f / rf2 : 0.f;
                float ttv = 0.5f * (rf2 - 1.f) * inv2;
                float gate = (rr > 0) ? 1.f : 0.f;
                float pre = buf[(uu * 4 + 0) * 64 + l] + buf[(uu * 4 + 1) * 64 + l]
                          + buf[(uu * 4 + 2) * 64 + l] + buf[(uu * 4 + 3) * 64 + l];
                float acc2 = wxv[25];
                float rr0 = 0.f, rr1 = 0.f, rr2 = 0.f;
#pragma unroll
                for (int c = 0; c < 10; ++c) {
                    float Fv = sF[rr * IND + c];
                    float rv = Fv - f0[c];
                    if (c == 0) rr0 = rv; else if (c == 1) rr1 = rv; else if (c == 2) rr2 = rv;
                    acc2 = fmaf(rv, wxv[c], acc2);
                    acc2 = fmaf(Fv, wxv[10 + c], acc2);
                }
                float ttc = wxv[20] + rr0 * wxv[21] + rr1 * wxv[22] + rr2 * wxv[23];
                pre += acc2 + ttv * ttc + gate * wxv[24];
                pre1[b * (NT * HID) + rr * HID + l] = pre;
            }
        }
    }
}

// ---------------------------------------------------------------------------
// scan v4: 2 batches per wave (b, b+512), grid 512.  LDS-b128 broadcast GEMV
// (r9-proven fast path; r10's readlane GEMV lost ~400 cyc/step to
// VALU->SGPR-read hazards), NO barriers, interleaved DPP reduces.  The two
// independent per-batch dependency chains overlap: the SIMD issues batch B's
// work during batch A's LDS/FMA latency (we are pinned at 1 wave/SIMD, so
// in-wave ILP is the only latency-hiding available).
// ---------------------------------------------------------------------------
__device__ __forceinline__ float rdlanef(float v, int i) {
    return __uint_as_float(__builtin_amdgcn_readlane(__float_as_uint(v), i));
}

template <int CTRL, int RMASK>
__device__ __forceinline__ float dpp_add(float x) {
    int v = __builtin_amdgcn_update_dpp(0, __float_as_int(x), CTRL, RMASK, 0xf, false);
    return x + __int_as_float(v);
}

#define W2_EACH(X) X(0) X(1) X(2) X(3) X(4) X(5) X(6) X(7) \
    X(8) X(9) X(10) X(11) X(12) X(13) X(14) X(15)

__global__ __launch_bounds__(64, 1) void scan4_kernel(
    const float* __restrict__ pre1, const float* __restrict__ W1,
    const float* __restrict__ W2, const float* __restrict__ b2,
    const float* __restrict__ W3, const float* __restrict__ b3,
    float* __restrict__ out) {
    const int bA = blockIdx.x;
    const int bB = blockIdx.x + 512;
    const int j = threadIdx.x;

    __shared__ __align__(16) float sHA[64];
    __shared__ __align__(16) float sHB[64];

#define DECLW(q) float4 w2_##q = make_float4( \
        W2[(4*(q)+0)*64 + j], W2[(4*(q)+1)*64 + j], \
        W2[(4*(q)+2)*64 + j], W2[(4*(q)+3)*64 + j]);
    W2_EACH(DECLW)
#undef DECLW
    float w1l = W1[522 * 64 + j];
    float b2j = b2[j], w3j = W3[j], b3v = b3[0];

    const float* pA = pre1 + bA * (NT * HID);
    const float* pB = pre1 + bB * (NT * HID);
    float dA = 0.f, dB = 0.f;
    float obA = 0.f, obB = 0.f;

#define GEMV2(q) { \
        float4 hA = *(const float4*)&sHA[4*(q)]; \
        float4 hB = *(const float4*)&sHB[4*(q)]; \
        aA0 = fmaf(hA.x, w2_##q.x, aA0); aB0 = fmaf(hB.x, w2_##q.x, aB0); \
        aA1 = fmaf(hA.y, w2_##q.y, aA1); aB1 = fmaf(hB.y, w2_##q.y, aB1); \
        aA2 = fmaf(hA.z, w2_##q.z, aA2); aB2 = fmaf(hB.z, w2_##q.z, aB2); \
        aA3 = fmaf(hA.w, w2_##q.w, aA3); aB3 = fmaf(hB.w, w2_##q.w, aB3); }

#define SCAN_STEP2(pvA, pvB, mm) { \
        float h1A = fmaxf(fmaf(dA, w1l, (pvA)), 0.f); \
        float h1B = fmaxf(fmaf(dB, w1l, (pvB)), 0.f); \
        sHA[j] = h1A; sHB[j] = h1B; \
        float aA0 = 0.f, aA1 = 0.f, aA2 = 0.f, aA3 = 0.f; \
        float aB0 = 0.f, aB1 = 0.f, aB2 = 0.f, aB3 = 0.f; \
        W2_EACH(GEMV2) \
        float h2A = fmaxf((aA0 + aA1) + (aA2 + aA3) + b2j, 0.f); \
        float h2B = fmaxf((aB0 + aB1) + (aB2 + aB3) + b2j, 0.f); \
        float qA = h2A * w3j, qB = h2B * w3j; \
        qA = dpp_add<0x111, 0xf>(qA); qB = dpp_add<0x111, 0xf>(qB); \
        qA = dpp_add<0x112, 0xf>(qA); qB = dpp_add<0x112, 0xf>(qB); \
        qA = dpp_add<0x114, 0xf>(qA); qB = dpp_add<0x114, 0xf>(qB); \
        qA = dpp_add<0x118, 0xf>(qA); qB = dpp_add<0x118, 0xf>(qB); \
        qA = dpp_add<0x142, 0xa>(qA); qB = dpp_add<0x142, 0xa>(qB); \
        qA = dpp_add<0x143, 0xc>(qA); qB = dpp_add<0x143, 0xc>(qB); \
        dA = rdlanef(qA, 63) + b3v; \
        dB = rdlanef(qB, 63) + b3v; \
        if (j == ((mm) & 63)) { obA = dA; obB = dB; } \
        if (((mm) & 63) == 63) { \
            out[bA * NT + ((mm) & ~63) + j] = obA; \
            out[bB * NT + ((mm) & ~63) + j] = obB; } }

    float rA0 = pA[0 * 64 + j], rA1 = pA[1 * 64 + j], rA2 = pA[2 * 64 + j],
          rA3 = pA[3 * 64 + j], rA4 = pA[4 * 64 + j], rA5 = pA[5 * 64 + j],
          rA6 = pA[6 * 64 + j], rA7 = pA[7 * 64 + j];
    float rB0 = pB[0 * 64 + j], rB1 = pB[1 * 64 + j], rB2 = pB[2 * 64 + j],
          rB3 = pB[3 * 64 + j], rB4 = pB[4 * 64 + j], rB5 = pB[5 * 64 + j],
          rB6 = pB[6 * 64 + j], rB7 = pB[7 * 64 + j];
    for (int g = 0; g < NT; g += 8) {
        int nb = g + 8;
        int i0 = min(nb + 0, NT - 1) * 64 + j, i1 = min(nb + 1, NT - 1) * 64 + j;
        int i2 = min(nb + 2, NT - 1) * 64 + j, i3 = min(nb + 3, NT - 1) * 64 + j;
        int i4 = min(nb + 4, NT - 1) * 64 + j, i5 = min(nb + 5, NT - 1) * 64 + j;
        int i6 = min(nb + 6, NT - 1) * 64 + j, i7 = min(nb + 7, NT - 1) * 64 + j;
        float nA0 = pA[i0], nA1 = pA[i1], nA2 = pA[i2], nA3 = pA[i3];
        float nA4 = pA[i4], nA5 = pA[i5], nA6 = pA[i6], nA7 = pA[i7];
        float nB0 = pB[i0], nB1 = pB[i1], nB2 = pB[i2], nB3 = pB[i3];
        float nB4 = pB[i4], nB5 = pB[i5], nB6 = pB[i6], nB7 = pB[i7];
        SCAN_STEP2(rA0, rB0, g + 0)
        SCAN_STEP2(rA1, rB1, g + 1)
        SCAN_STEP2(rA2, rB2, g + 2)
        SCAN_STEP2(rA3, rB3, g + 3)
        SCAN_STEP2(rA4, rB4, g + 4)
        SCAN_STEP2(rA5, rB5, g + 5)
        SCAN_STEP2(rA6, rB6, g + 6)
        SCAN_STEP2(rA7, rB7, g + 7)
        rA0 = nA0; rA1 = nA1; rA2 = nA2; rA3 = nA3;
        rA4 = nA4; rA5 = nA5; rA6 = nA6; rA7 = nA7;
        rB0 = nB0; rB1 = nB1; rB2 = nB2; rB3 = nB3;
        rB4 = nB4; rB5 = nB5; rB6 = nB6; rB7 = nB7;
    }
#undef SCAN_STEP2
#undef GEMV2
}

// ---------------------------------------------------------------------------
// Fallback (round-1 fused kernel) if workspace is too small.
// ---------------------------------------------------------------------------
__global__ __launch_bounds__(256) void logsig_hedge_fallback(
    const float* __restrict__ features, const float* __restrict__ W1,
    const float* __restrict__ b1, const float* __restrict__ W2,
    const float* __restrict__ b2, const float* __restrict__ W3,
    const float* __restrict__ b3, float* __restrict__ out) {
    const int b = blockIdx.x;
    const int tid = threadIdx.x;
    const int j = tid & 63;
    const int s = tid >> 6;

    __shared__ __align__(16) float sF[NT * IND];
    __shared__ __align__(16) float sSig[128];
    __shared__ float sA[IND], sB[IND], sC[IND * IND];
    __shared__ float sRel[IND];
    __shared__ __align__(16) float sPart[4 * 64];
    __shared__ __align__(16) float sH1[64];

    for (int idx = tid; idx < NT * IND; idx += 256)
        sF[idx] = features[b * (NT * IND) + idx];
    if (tid < 100) sC[tid] = 0.f;
    else if (tid < 110) sA[tid - 100] = 0.f;
    else if (tid < 120) sB[tid - 110] = 0.f;
    else if (tid >= 121 && tid < 128) sSig[tid] = 0.f;

    float vs[32], vb[32], vc[32];
#pragma unroll
    for (int mm = 0; mm < 32; ++mm) {
        int mp = 32 * s + mm;
        if (mp < 121) {
            vs[mm] = W1[(11 + mp) * 64 + j] + W1[(132 + mp) * 64 + j];
            vb[mm] = W1[(253 + mp) * 64 + j];
            vc[mm] = W1[(374 + mp) * 64 + j];
        } else { vs[mm] = 0.f; vb[mm] = 0.f; vc[mm] = 0.f; }
    }
    float ex[17];
#pragma unroll
    for (int q = 0; q < 17; ++q) ex[q] = 0.f;
    if (s == 1) {
#pragma unroll
        for (int q = 0; q < 11; ++q) ex[q] = W1[q * 64 + j];
    } else if (s == 2) {
#pragma unroll
        for (int q = 0; q < 10; ++q) ex[q] = W1[(512 + q) * 64 + j];
        ex[10] = b1[j];
    } else if (s == 3) {
#pragma unroll
        for (int q = 0; q < 17; ++q) ex[q] = W1[(495 + q) * 64 + j];
    }
    float w2p[16];
#pragma unroll
    for (int ii = 0; ii < 16; ++ii) w2p[ii] = W2[(16 * s + ii) * 64 + j];

    float w1l = 0.f, b2j = 0.f, w3j = 0.f, b3v = 0.f;
    if (s == 0) { w1l = W1[522 * 64 + j]; b2j = b2[j]; w3j = W3[j]; b3v = b3[0]; }
    float delta = 0.f;

    __syncthreads();

    for (int m = 0; m < NT; ++m) {
        if (m > 0) {
            if (tid < 100) {
                int i = tid / 10, c = tid % 10;
                float rp = sF[(m - 1) * 10 + i] - sF[i];
                float ic = sF[m * 10 + c] - sF[(m - 1) * 10 + c];
                sC[tid] += rp * ic;
            } else if (tid < 110) {
                int i = tid - 100;
                sA[i] += (float)(m - 1) * (sF[m * 10 + i] - sF[(m - 1) * 10 + i]);
            } else if (tid < 120) {
                int i = tid - 110;
                sB[i] += sF[(m - 1) * 10 + i] - sF[i];
            }
            __syncthreads();
            float inv_k = 1.0f / (float)m;
            if (tid == 0) sSig[0] = 0.5f * (float)(m - 1) * inv_k;
            else if (tid < 11) sSig[tid] = inv_k * sA[tid - 1];
            else if (tid < 121) {
                int i = tid / 11 - 1, c = tid % 11;
                sSig[tid] = (c == 0) ? inv_k * sB[i] : sC[i * 10 + (c - 1)];
            } else if (tid < 131) {
                int f = tid - 121;
                sRel[f] = sF[m * 10 + f] - sF[f];
            }
            __syncthreads();
        }
        float part = 0.f;
        if (m > 0) {
            float pa = 0.f, pb = 0.f, pc = 0.f;
#pragma unroll
            for (int q = 0; q < 8; ++q) {
                float4 sv = *(const float4*)&sSig[32 * s + 4 * q];
                pa = fmaf(sv.x, vs[4 * q + 0], pa);
                pb = fmaf(sv.x, vb[4 * q + 0], pb);
                pc = fmaf(sv.x, vc[4 * q + 0], pc);
                pa = fmaf(sv.y, vs[4 * q + 1], pa);
                pb = fmaf(sv.y, vb[4 * q + 1], pb);
                pc = fmaf(sv.y, vc[4 * q + 1], pc);
                pa = fmaf(sv.z, vs[4 * q + 2], pa);
                pb = fmaf(sv.z, vb[4 * q + 2], pb);
                pc = fmaf(sv.z, vc[4 * q + 2], pc);
                pa = fmaf(sv.w, vs[4 * q + 3], pa);
                pb = fmaf(sv.w, vb[4 * q + 3], pb);
                pc = fmaf(sv.w, vc[4 * q + 3], pc);
            }
            part = pa + sRel[0] * pb + sRel[1] * pc;
            if (s == 3) {
                float pd = 0.f;
#pragma unroll
                for (int q = 0; q < 17; ++q) pd = fmaf(sSig[q], ex[q], pd);
                part = fmaf(sRel[2], pd, part);
            }
            if (s == 1) {
                part += ex[0];
#pragma unroll
                for (int i = 0; i < 10; ++i) part = fmaf(sRel[i], ex[1 + i], part);
            }
        }
        if (s == 2) {
            float pf = ex[10];
#pragma unroll
            for (int f = 0; f < 10; ++f) pf = fmaf(sF[m * 10 + f], ex[f], pf);
            part += pf;
        }
        sPart[s * 64 + j] = part;
        __syncthreads();
        if (s == 0) {
            float x = sPart[j] + sPart[64 + j] + sPart[128 + j] + sPart[192 + j];
            sH1[j] = fmaxf(fmaf(delta, w1l, x), 0.f);
        }
        __syncthreads();
        {
            float hp = 0.f;
#pragma unroll
            for (int q = 0; q < 4; ++q) {
                float4 hv = *(const float4*)&sH1[16 * s + 4 * q];
                hp = fmaf(hv.x, w2p[4 * q + 0], hp);
                hp = fmaf(hv.y, w2p[4 * q + 1], hp);
                hp = fmaf(hv.z, w2p[4 * q + 2], hp);
                hp = fmaf(hv.w, w2p[4 * q + 3], hp);
            }
            sPart[s * 64 + j] = hp;
        }
        __syncthreads();
        if (s == 0) {
            float x2 = sPart[j] + sPart[64 + j] + sPart[128 + j] + sPart[192 + j] + b2j;
            float h2 = fmaxf(x2, 0.f);
            float dv = h2 * w3j;
#pragma unroll
            for (int off = 32; off > 0; off >>= 1) dv += __shfl_xor(dv, off, 64);
            delta = dv + b3v;
            if (j == 0) out[b * NT + m] = delta;
        }
        __syncthreads();
    }
}

extern "C" void kernel_launch(void* const* d_in, const int* in_sizes, int n_in,
                              void* d_out, int out_size, void* d_ws, size_t ws_size,
                              hipStream_t stream) {
    const float* features = (const float*)d_in[0];
    const float* W1 = (const float*)d_in[1];
    const float* b1 = (const float*)d_in[2];
    const float* W2 = (const float*)d_in[3];
    const float* b2 = (const float*)d_in[4];
    const float* W3 = (const float*)d_in[5];
    const float* b3 = (const float*)d_in[6];
    float* out = (float*)d_out;

    const size_t w_pad     = (((size_t)WP_FLOATS * 4 + 255) / 256) * 256;
    const size_t pre_bytes = (size_t)NB * NT * HID * sizeof(float);  // 64 MiB
    if (ws_size >= w_pad + pre_bytes) {
        float* Wp = (float*)d_ws;
        float* pre1 = (float*)((char*)d_ws + w_pad);
        pack_kernel<<<(WP_FLOATS + 255) / 256, 256, 0, stream>>>(W1, b1, Wp);
        presig6_kernel<<<NB, 256, 0, stream>>>(features, Wp, pre1);
        scan4_kernel<<<512, 64, 0, stream>>>(pre1, W1, W2, b2, W3, b3, out);
    } else {
        logsig_hedge_fallback<<<NB, 256, 0, stream>>>(features, W1, b1, W2, b2, W3, b3, out);
    }
}

// Round 12
// 432.106 us; speedup vs baseline: 1.1713x; 1.1713x over previous
//
#include <hip/hip_runtime.h>

#define NB 1024
#define NT 256
#define IND 10
#define HID 64

// Packed weight array Wp (float offsets), all [k][64j] lane-coalesced:
//   OFF_WA [120][64]: W1[11+q]+W1[132+q]   (q = qmap(k))
//   OFF_WB [120][64]: W1[253+q]            (gated by rel0)
//   OFF_WC [120][64]: W1[374+q]            (gated by rel1)
//   OFF_WD [16][64] : rel2-gated 17-term weights (sig2f[1..16] part)
//   OFF_WX [28][64] : 0-9 wrel, 10-19 wf, 20-23 tt coefs (ws,wb,wc,wd),
//                     24 w_one, 25 b1, 26-27 pad
#define OFF_WA 0
#define OFF_WB 7680
#define OFF_WC 15360
#define OFF_WD 23040
#define OFF_WX 24064
#define WP_FLOATS 25856

__device__ __forceinline__ int qmap(int kk) {
    if (kk < 10) return 1 + kk;
    if (kk < 20) return 11 * (kk - 10 + 1);
    int i = (kk - 20) / 10, c = (kk - 20) % 10;
    return 11 * (i + 1) + 1 + c;
}

__global__ void pack_kernel(const float* __restrict__ W1, const float* __restrict__ b1,
                            float* __restrict__ Wp) {
    int idx = blockIdx.x * 256 + threadIdx.x;
    if (idx >= WP_FLOATS) return;
    float v = 0.f;
    if (idx < OFF_WB) {
        int k = idx >> 6, j = idx & 63; int q = qmap(k);
        v = W1[(11 + q) * 64 + j] + W1[(132 + q) * 64 + j];
    } else if (idx < OFF_WC) {
        int e = idx - OFF_WB; int k = e >> 6, j = e & 63;
        v = W1[(253 + qmap(k)) * 64 + j];
    } else if (idx < OFF_WD) {
        int e = idx - OFF_WC; int k = e >> 6, j = e & 63;
        v = W1[(374 + qmap(k)) * 64 + j];
    } else if (idx < OFF_WX) {
        int e = idx - OFF_WD; int i = e >> 6, j = e & 63;
        if (i < 10)       v = W1[(496 + i) * 64 + j];
        else if (i == 10) v = W1[506 * 64 + j];
        else if (i < 16)  v = W1[(507 + (i - 11)) * 64 + j];
    } else {
        int e = idx - OFF_WX; int o = e >> 6, j = e & 63;
        if (o < 10)       v = W1[(1 + o) * 64 + j];
        else if (o < 20)  v = W1[(512 + o - 10) * 64 + j];
        else if (o == 20) v = W1[11 * 64 + j] + W1[132 * 64 + j];
        else if (o == 21) v = W1[253 * 64 + j];
        else if (o == 22) v = W1[374 * 64 + j];
        else if (o == 23) v = W1[495 * 64 + j];
        else if (o == 24) v = W1[0 * 64 + j];
        else if (o == 25) v = b1[j];
    }
    Wp[idx] = v;
}

// ---------------------------------------------------------------------------
// presig v7 = presig6 (r10, 298 us) minus the Bb barrier: sP and sBase are
// INTRA-WAVE (wave wu writes slice 32*wu at lane=t and reads only that
// slice) -> in-order lgkmcnt gives write->read ordering within the wave;
// no cross-wave hazard exists.  Remaining barriers: B0 once, Bq1 x4 per
// tile (sAcc genuinely crosses waves).
// ---------------------------------------------------------------------------
__global__ __launch_bounds__(256, 1) void presig7_kernel(
    const float* __restrict__ features, const float* __restrict__ Wp,
    float* __restrict__ pre1) {
    const int b = blockIdx.x;
    const int tid = threadIdx.x;
    const int l = tid & 63;
    const int wu = tid >> 6;

    __shared__ __align__(16) float sF[NT * IND];
    __shared__ __align__(16) float sP[64 * 132];
    __shared__ __align__(16) float sAcc[2][16 * 4 * 64];
    __shared__ float sBase[128];

    {
        const float4* src = (const float4*)(features + b * (NT * IND));
        float4* dst = (float4*)sF;
        for (int e = tid; e < NT * IND / 4; e += 256) dst[e] = src[e];
    }
    float f0[IND];
#pragma unroll
    for (int c = 0; c < IND; ++c) f0[c] = features[b * (NT * IND) + c];

    float wxv[26];
#pragma unroll
    for (int o = 0; o < 26; ++o) wxv[o] = Wp[OFF_WX + o * 64 + l];

    if (tid < 128) sBase[tid] = 0.f;
    __syncthreads();   // B0: sF + sBase ready

    for (int tile = 0; tile < 4; ++tile) {
        const int t0 = tile * 64;

        // ---- scan phase (spill-free wave scan, intra-wave sP/sBase) ----
        const int r = t0 + l;
        float rf = (float)r;
        float fr[IND], rel[IND], inc[IND];
#pragma unroll
        for (int c = 0; c < IND; ++c) fr[c] = sF[r * IND + c];
#pragma unroll
        for (int c = 0; c < IND; ++c) rel[c] = fr[c] - f0[c];
        {
            bool last = (r >= NT - 1);
#pragma unroll
            for (int c = 0; c < IND; ++c)
                inc[c] = last ? 0.f : (sF[(r + 1) * IND + c] - fr[c]);
        }
        float p[30], own[30];
        if (wu == 0) {
#pragma unroll
            for (int c = 0; c < 10; ++c) p[c] = rf * inc[c];
#pragma unroll
            for (int i = 0; i < 10; ++i) p[10 + i] = rel[i];
#pragma unroll
            for (int c = 0; c < 10; ++c) p[20 + c] = rel[0] * inc[c];
        } else {
            const int i0 = 3 * wu - 2;
#pragma unroll
            for (int q = 0; q < 30; ++q) {
                int i = i0 + q / 10, c = q % 10;
                p[q] = rel[i] * inc[c];
            }
        }
#pragma unroll
        for (int i = 0; i < 30; ++i) own[i] = p[i];
#pragma unroll
        for (int dsh = 0; dsh < 6; ++dsh) {
            const int d = 1 << dsh;
            bool ok = (l >= d);
#pragma unroll
            for (int i = 0; i < 30; ++i) {
                float v = __shfl_up(p[i], d, 64);
                if (ok) p[i] += v;
            }
        }
        float inv_r = (r > 0) ? 1.f / rf : 0.f;
#pragma unroll
        for (int i = 0; i < 30; ++i) {
            float v = sBase[wu * 32 + i] + p[i] - own[i];
            if (wu == 0 && i < 20) v *= inv_r;
            sP[l * 132 + 32 * wu + i] = v;
        }
        if (l == 63) {   // wave-exclusive slice; in-wave order suffices
#pragma unroll
            for (int i = 0; i < 30; ++i) sBase[wu * 32 + i] += p[i];
        }
        // NO Bb barrier: sP/sBase are intra-wave; lgkmcnt orders write->read.

        // ---- per-tile weight regs; asm pin blocks LICM hoist into scan ----
        int kbase = 30 * wu;
        asm volatile("" : "+v"(kbase));
        float wav[30], wbv[30], wcv[30];
#pragma unroll
        for (int i = 0; i < 30; ++i) {
            int k = kbase + i;
            wav[i] = Wp[OFF_WA + (k << 6) + l];
            wbv[i] = Wp[OFF_WB + (k << 6) + l];
            wcv[i] = Wp[OFF_WC + (k << 6) + l];
        }
        float wdv[16];
#pragma unroll
        for (int i = 0; i < 16; ++i) wdv[i] = Wp[OFF_WD + (i << 6) + l];

        // ---- j-phase: 4 quarters of 16 t's, double-buffered sAcc ----
#pragma unroll 1
        for (int tq = 0; tq < 4; ++tq) {
            float* buf = sAcc[tq & 1];
#pragma unroll 1
            for (int u = 0; u < 16; ++u) {
                int t = tq * 16 + u;
                const float4* Pp = (const float4*)&sP[t * 132 + 32 * wu];
                float4 q0 = Pp[0], q1 = Pp[1], q2 = Pp[2], q3 = Pp[3];
                float4 q4 = Pp[4], q5 = Pp[5], q6 = Pp[6], q7 = Pp[7];
                float rr0 = sF[(t0 + t) * IND + 0] - f0[0];
                float rr1 = sF[(t0 + t) * IND + 1] - f0[1];
                float rr2 = sF[(t0 + t) * IND + 2] - f0[2];
                float a = 0.f, bb = 0.f, cv = 0.f;
#define FMA4(QQ, BASE) \
                a  = fmaf(QQ.x, wav[BASE+0], a);  a  = fmaf(QQ.y, wav[BASE+1], a); \
                a  = fmaf(QQ.z, wav[BASE+2], a);  a  = fmaf(QQ.w, wav[BASE+3], a); \
                bb = fmaf(QQ.x, wbv[BASE+0], bb); bb = fmaf(QQ.y, wbv[BASE+1], bb); \
                bb = fmaf(QQ.z, wbv[BASE+2], bb); bb = fmaf(QQ.w, wbv[BASE+3], bb); \
                cv = fmaf(QQ.x, wcv[BASE+0], cv); cv = fmaf(QQ.y, wcv[BASE+1], cv); \
                cv = fmaf(QQ.z, wcv[BASE+2], cv); cv = fmaf(QQ.w, wcv[BASE+3], cv);
                FMA4(q0, 0) FMA4(q1, 4) FMA4(q2, 8) FMA4(q3, 12)
                FMA4(q4, 16) FMA4(q5, 20) FMA4(q6, 24)
#undef FMA4
                a  = fmaf(q7.x, wav[28], a);  a  = fmaf(q7.y, wav[29], a);
                bb = fmaf(q7.x, wbv[28], bb); bb = fmaf(q7.y, wbv[29], bb);
                cv = fmaf(q7.x, wcv[28], cv); cv = fmaf(q7.y, wcv[29], cv);
                float val = a + rr0 * bb + rr1 * cv;
                if (wu == 0) {
                    float dd = 0.f;
                    dd = fmaf(q0.x, wdv[0], dd); dd = fmaf(q0.y, wdv[1], dd);
                    dd = fmaf(q0.z, wdv[2], dd); dd = fmaf(q0.w, wdv[3], dd);
                    dd = fmaf(q1.x, wdv[4], dd); dd = fmaf(q1.y, wdv[5], dd);
                    dd = fmaf(q1.z, wdv[6], dd); dd = fmaf(q1.w, wdv[7], dd);
                    dd = fmaf(q2.x, wdv[8], dd); dd = fmaf(q2.y, wdv[9], dd);
                    dd = fmaf(q2.z, wdv[10], dd);
                    dd = fmaf(q5.x, wdv[11], dd); dd = fmaf(q5.y, wdv[12], dd);
                    dd = fmaf(q5.z, wdv[13], dd); dd = fmaf(q5.w, wdv[14], dd);
                    dd = fmaf(q6.x, wdv[15], dd);
                    val = fmaf(rr2, dd, val);
                }
                buf[(u * 4 + wu) * 64 + l] = val;
            }
            __syncthreads();   // Bq1: buf ready (cross-wave)
#pragma unroll 1
            for (int u = 0; u < 4; ++u) {
                int uu = wu * 4 + u;
                int t = tq * 16 + uu;
                int rr = t0 + t;
                float rf2 = (float)rr;
                float inv2 = (rr > 0) ? 1.f / rf2 : 0.f;
                float ttv = 0.5f * (rf2 - 1.f) * inv2;
                float gate = (rr > 0) ? 1.f : 0.f;
                float pre = buf[(uu * 4 + 0) * 64 + l] + buf[(uu * 4 + 1) * 64 + l]
                          + buf[(uu * 4 + 2) * 64 + l] + buf[(uu * 4 + 3) * 64 + l];
                float acc2 = wxv[25];
                float rr0 = 0.f, rr1 = 0.f, rr2 = 0.f;
#pragma unroll
                for (int c = 0; c < 10; ++c) {
                    float Fv = sF[rr * IND + c];
                    float rv = Fv - f0[c];
                    if (c == 0) rr0 = rv; else if (c == 1) rr1 = rv; else if (c == 2) rr2 = rv;
                    acc2 = fmaf(rv, wxv[c], acc2);
                    acc2 = fmaf(Fv, wxv[10 + c], acc2);
                }
                float ttc = wxv[20] + rr0 * wxv[21] + rr1 * wxv[22] + rr2 * wxv[23];
                pre += acc2 + ttv * ttc + gate * wxv[24];
                pre1[b * (NT * HID) + rr * HID + l] = pre;
            }
            // no Bq2: double buffer; reuse separated by Bq1(next)/Bq1(next tile).
        }
    }
}

// ---------------------------------------------------------------------------
// scan (r9-proven, ~120 us): 1 wave per batch, grid 1024.  LDS-b128
// broadcast GEMV, NO barriers (single-wave lgkmcnt ordering), DPP reduce,
// 8-deep global prefetch ring.  r10's readlane GEMV (+52 us: VALU->SGPR
// hazards) and r11's 2-batch interleave (+83 us: half the SIMDs idle,
// shared lgkm drains) both regressed — this is the measured optimum.
// ---------------------------------------------------------------------------
template <int CTRL, int RMASK>
__device__ __forceinline__ float dpp_add(float x) {
    int v = __builtin_amdgcn_update_dpp(0, __float_as_int(x), CTRL, RMASK, 0xf, false);
    return x + __int_as_float(v);
}

#define W2_EACH(X) X(0) X(1) X(2) X(3) X(4) X(5) X(6) X(7) \
    X(8) X(9) X(10) X(11) X(12) X(13) X(14) X(15)

__global__ __launch_bounds__(64, 1) void scan_kernel(
    const float* __restrict__ pre1, const float* __restrict__ W1,
    const float* __restrict__ W2, const float* __restrict__ b2,
    const float* __restrict__ W3, const float* __restrict__ b3,
    float* __restrict__ out) {
    const int b = blockIdx.x;
    const int j = threadIdx.x;

    __shared__ __align__(16) float sH[64];

#define DECLW(q) float4 w2_##q = make_float4( \
        W2[(4*(q)+0)*64 + j], W2[(4*(q)+1)*64 + j], \
        W2[(4*(q)+2)*64 + j], W2[(4*(q)+3)*64 + j]);
    W2_EACH(DECLW)
#undef DECLW
    float w1l = W1[522 * 64 + j];
    float b2j = b2[j], w3j = W3[j], b3v = b3[0];

    const float* pb_ = pre1 + b * (NT * HID);
    float delta = 0.f;
    float outbuf = 0.f;

#define GEMVQ(q) { float4 h4 = *(const float4*)&sH[4*(q)]; \
        a0 = fmaf(h4.x, w2_##q.x, a0); a1 = fmaf(h4.y, w2_##q.y, a1); \
        a2 = fmaf(h4.z, w2_##q.z, a2); a3 = fmaf(h4.w, w2_##q.w, a3); }

#define SCAN_STEP(pv, mm) { \
        float h1 = fmaxf(fmaf(delta, w1l, (pv)), 0.f); \
        sH[j] = h1; \
        float a0 = 0.f, a1 = 0.f, a2 = 0.f, a3 = 0.f; \
        W2_EACH(GEMVQ) \
        float h2 = fmaxf((a0 + a1) + (a2 + a3) + b2j, 0.f); \
        float qv = h2 * w3j; \
        qv = dpp_add<0x111, 0xf>(qv); \
        qv = dpp_add<0x112, 0xf>(qv); \
        qv = dpp_add<0x114, 0xf>(qv); \
        qv = dpp_add<0x118, 0xf>(qv); \
        qv = dpp_add<0x142, 0xa>(qv); \
        qv = dpp_add<0x143, 0xc>(qv); \
        float tot = __uint_as_float(__builtin_amdgcn_readlane(__float_as_uint(qv), 63)); \
        delta = tot + b3v; \
        if (j == ((mm) & 63)) outbuf = delta; \
        if (((mm) & 63) == 63) out[b * NT + ((mm) & ~63) + j] = outbuf; }

    float r0 = pb_[0 * 64 + j], r1 = pb_[1 * 64 + j], r2 = pb_[2 * 64 + j],
          r3 = pb_[3 * 64 + j], r4 = pb_[4 * 64 + j], r5 = pb_[5 * 64 + j],
          r6 = pb_[6 * 64 + j], r7 = pb_[7 * 64 + j];
    for (int g = 0; g < NT; g += 8) {
        int nb = g + 8;
        float n0 = pb_[min(nb + 0, NT - 1) * 64 + j];
        float n1 = pb_[min(nb + 1, NT - 1) * 64 + j];
        float n2 = pb_[min(nb + 2, NT - 1) * 64 + j];
        float n3 = pb_[min(nb + 3, NT - 1) * 64 + j];
        float n4 = pb_[min(nb + 4, NT - 1) * 64 + j];
        float n5 = pb_[min(nb + 5, NT - 1) * 64 + j];
        float n6 = pb_[min(nb + 6, NT - 1) * 64 + j];
        float n7 = pb_[min(nb + 7, NT - 1) * 64 + j];
        SCAN_STEP(r0, g + 0)
        SCAN_STEP(r1, g + 1)
        SCAN_STEP(r2, g + 2)
        SCAN_STEP(r3, g + 3)
        SCAN_STEP(r4, g + 4)
        SCAN_STEP(r5, g + 5)
        SCAN_STEP(r6, g + 6)
        SCAN_STEP(r7, g + 7)
        r0 = n0; r1 = n1; r2 = n2; r3 = n3; r4 = n4; r5 = n5; r6 = n6; r7 = n7;
    }
#undef SCAN_STEP
#undef GEMVQ
}

// ---------------------------------------------------------------------------
// Fallback (round-1 fused kernel) if workspace is too small.
// ---------------------------------------------------------------------------
__global__ __launch_bounds__(256) void logsig_hedge_fallback(
    const float* __restrict__ features, const float* __restrict__ W1,
    const float* __restrict__ b1, const float* __restrict__ W2,
    const float* __restrict__ b2, const float* __restrict__ W3,
    const float* __restrict__ b3, float* __restrict__ out) {
    const int b = blockIdx.x;
    const int tid = threadIdx.x;
    const int j = tid & 63;
    const int s = tid >> 6;

    __shared__ __align__(16) float sF[NT * IND];
    __shared__ __align__(16) float sSig[128];
    __shared__ float sA[IND], sB[IND], sC[IND * IND];
    __shared__ float sRel[IND];
    __shared__ __align__(16) float sPart[4 * 64];
    __shared__ __align__(16) float sH1[64];

    for (int idx = tid; idx < NT * IND; idx += 256)
        sF[idx] = features[b * (NT * IND) + idx];
    if (tid < 100) sC[tid] = 0.f;
    else if (tid < 110) sA[tid - 100] = 0.f;
    else if (tid < 120) sB[tid - 110] = 0.f;
    else if (tid >= 121 && tid < 128) sSig[tid] = 0.f;

    float vs[32], vb[32], vc[32];
#pragma unroll
    for (int mm = 0; mm < 32; ++mm) {
        int mp = 32 * s + mm;
        if (mp < 121) {
            vs[mm] = W1[(11 + mp) * 64 + j] + W1[(132 + mp) * 64 + j];
            vb[mm] = W1[(253 + mp) * 64 + j];
            vc[mm] = W1[(374 + mp) * 64 + j];
        } else { vs[mm] = 0.f; vb[mm] = 0.f; vc[mm] = 0.f; }
    }
    float ex[17];
#pragma unroll
    for (int q = 0; q < 17; ++q) ex[q] = 0.f;
    if (s == 1) {
#pragma unroll
        for (int q = 0; q < 11; ++q) ex[q] = W1[q * 64 + j];
    } else if (s == 2) {
#pragma unroll
        for (int q = 0; q < 10; ++q) ex[q] = W1[(512 + q) * 64 + j];
        ex[10] = b1[j];
    } else if (s == 3) {
#pragma unroll
        for (int q = 0; q < 17; ++q) ex[q] = W1[(495 + q) * 64 + j];
    }
    float w2p[16];
#pragma unroll
    for (int ii = 0; ii < 16; ++ii) w2p[ii] = W2[(16 * s + ii) * 64 + j];

    float w1l = 0.f, b2j = 0.f, w3j = 0.f, b3v = 0.f;
    if (s == 0) { w1l = W1[522 * 64 + j]; b2j = b2[j]; w3j = W3[j]; b3v = b3[0]; }
    float delta = 0.f;

    __syncthreads();

    for (int m = 0; m < NT; ++m) {
        if (m > 0) {
            if (tid < 100) {
                int i = tid / 10, c = tid % 10;
                float rp = sF[(m - 1) * 10 + i] - sF[i];
                float ic = sF[m * 10 + c] - sF[(m - 1) * 10 + c];
                sC[tid] += rp * ic;
            } else if (tid < 110) {
                int i = tid - 100;
                sA[i] += (float)(m - 1) * (sF[m * 10 + i] - sF[(m - 1) * 10 + i]);
            } else if (tid < 120) {
                int i = tid - 110;
                sB[i] += sF[(m - 1) * 10 + i] - sF[i];
            }
            __syncthreads();
            float inv_k = 1.0f / (float)m;
            if (tid == 0) sSig[0] = 0.5f * (float)(m - 1) * inv_k;
            else if (tid < 11) sSig[tid] = inv_k * sA[tid - 1];
            else if (tid < 121) {
                int i = tid / 11 - 1, c = tid % 11;
                sSig[tid] = (c == 0) ? inv_k * sB[i] : sC[i * 10 + (c - 1)];
            } else if (tid < 131) {
                int f = tid - 121;
                sRel[f] = sF[m * 10 + f] - sF[f];
            }
            __syncthreads();
        }
        float part = 0.f;
        if (m > 0) {
            float pa = 0.f, pb = 0.f, pc = 0.f;
#pragma unroll
            for (int q = 0; q < 8; ++q) {
                float4 sv = *(const float4*)&sSig[32 * s + 4 * q];
                pa = fmaf(sv.x, vs[4 * q + 0], pa);
                pb = fmaf(sv.x, vb[4 * q + 0], pb);
                pc = fmaf(sv.x, vc[4 * q + 0], pc);
                pa = fmaf(sv.y, vs[4 * q + 1], pa);
                pb = fmaf(sv.y, vb[4 * q + 1], pb);
                pc = fmaf(sv.y, vc[4 * q + 1], pc);
                pa = fmaf(sv.z, vs[4 * q + 2], pa);
                pb = fmaf(sv.z, vb[4 * q + 2], pb);
                pc = fmaf(sv.z, vc[4 * q + 2], pc);
                pa = fmaf(sv.w, vs[4 * q + 3], pa);
                pb = fmaf(sv.w, vb[4 * q + 3], pb);
                pc = fmaf(sv.w, vc[4 * q + 3], pc);
            }
            part = pa + sRel[0] * pb + sRel[1] * pc;
            if (s == 3) {
                float pd = 0.f;
#pragma unroll
                for (int q = 0; q < 17; ++q) pd = fmaf(sSig[q], ex[q], pd);
                part = fmaf(sRel[2], pd, part);
            }
            if (s == 1) {
                part += ex[0];
#pragma unroll
                for (int i = 0; i < 10; ++i) part = fmaf(sRel[i], ex[1 + i], part);
            }
        }
        if (s == 2) {
            float pf = ex[10];
#pragma unroll
            for (int f = 0; f < 10; ++f) pf = fmaf(sF[m * 10 + f], ex[f], pf);
            part += pf;
        }
        sPart[s * 64 + j] = part;
        __syncthreads();
        if (s == 0) {
            float x = sPart[j] + sPart[64 + j] + sPart[128 + j] + sPart[192 + j];
            sH1[j] = fmaxf(fmaf(delta, w1l, x), 0.f);
        }
        __syncthreads();
        {
            float hp = 0.f;
#pragma unroll
            for (int q = 0; q < 4; ++q) {
                float4 hv = *(const float4*)&sH1[16 * s + 4 * q];
                hp = fmaf(hv.x, w2p[4 * q + 0], hp);
                hp = fmaf(hv.y, w2p[4 * q + 1], hp);
                hp = fmaf(hv.z, w2p[4 * q + 2], hp);
                hp = fmaf(hv.w, w2p[4 * q + 3], hp);
            }
            sPart[s * 64 + j] = hp;
        }
        __syncthreads();
        if (s == 0) {
            float x2 = sPart[j] + sPart[64 + j] + sPart[128 + j] + sPart[192 + j] + b2j;
            float h2 = fmaxf(x2, 0.f);
            float dv = h2 * w3j;
#pragma unroll
            for (int off = 32; off > 0; off >>= 1) dv += __shfl_xor(dv, off, 64);
            delta = dv + b3v;
            if (j == 0) out[b * NT + m] = delta;
        }
        __syncthreads();
    }
}

extern "C" void kernel_launch(void* const* d_in, const int* in_sizes, int n_in,
                              void* d_out, int out_size, void* d_ws, size_t ws_size,
                              hipStream_t stream) {
    const float* features = (const float*)d_in[0];
    const float* W1 = (const float*)d_in[1];
    const float* b1 = (const float*)d_in[2];
    const float* W2 = (const float*)d_in[3];
    const float* b2 = (const float*)d_in[4];
    const float* W3 = (const float*)d_in[5];
    const float* b3 = (const float*)d_in[6];
    float* out = (float*)d_out;

    const size_t w_pad     = (((size_t)WP_FLOATS * 4 + 255) / 256) * 256;
    const size_t pre_bytes = (size_t)NB * NT * HID * sizeof(float);  // 64 MiB
    if (ws_size >= w_pad + pre_bytes) {
        float* Wp = (float*)d_ws;
        float* pre1 = (float*)((char*)d_ws + w_pad);
        pack_kernel<<<(WP_FLOATS + 255) / 256, 256, 0, stream>>>(W1, b1, Wp);
        presig7_kernel<<<NB, 256, 0, stream>>>(features, Wp, pre1);
        scan_kernel<<<NB, 64, 0, stream>>>(pre1, W1, W2, b2, W3, b3, out);
    } else {
        logsig_hedge_fallback<<<NB, 256, 0, stream>>>(features, W1, b1, W2, b2, W3, b3, out);
    }
}